// Round 1
// baseline (1133.978 us; speedup 1.0000x reference)
//
#include <hip/hip_runtime.h>

#define DEVFN __device__ __forceinline__

static constexpr int cB  = 16;
static constexpr int cS  = 1024;
static constexpr int cD  = 1024;
static constexpr int cPE = 20;
static constexpr int cG  = 80;   // 4*PE

typedef float  floatx2 __attribute__((ext_vector_type(2)));
typedef float  floatx4 __attribute__((ext_vector_type(4)));
typedef short  short8  __attribute__((ext_vector_type(8)));

DEVFN float fsig(float x) { return __builtin_amdgcn_rcpf(1.f + __expf(-x)); }
DEVFN float ftanh(float x) {
  x = fminf(fmaxf(x, -15.f), 15.f);
  float e = __expf(2.f * x);
  return (e - 1.f) * __builtin_amdgcn_rcpf(e + 1.f);
}
DEVFN unsigned pack_bf(float a, float b) {
  union { float f; unsigned u; } ua, ub; ua.f = a; ub.f = b;
  return (ua.u >> 16) | (ub.u & 0xffff0000u);
}

// ---------------------------------------------------------------------------
// K1: xg[b,s,g] = sum_d x[b,s,d]*W_ih[g,d] + b_ih[g] + b_hh[g]
//     also emits x in bf16 (truncated) for the K4 MFMA if workspace allows.
// One wave per row (B*S = 16384 rows), lane owns 16 consecutive K elements.
// ---------------------------------------------------------------------------
__global__ __launch_bounds__(256) void k1_xg(
    const float* __restrict__ x, const float* __restrict__ W_ih,
    const float* __restrict__ b_ih, const float* __restrict__ b_hh,
    float* __restrict__ xg, unsigned short* __restrict__ xbf, int use_bf)
{
  const int lane = threadIdx.x & 63;
  const int row  = blockIdx.x * 4 + (threadIdx.x >> 6);   // 0..16383
  const float4* xr = (const float4*)(x + (size_t)row * cD + lane * 16);
  float4 a0 = xr[0], a1 = xr[1], a2 = xr[2], a3 = xr[3];

  if (use_bf) {
    unsigned u[8];
    const float* f = (const float*)&a0;   // a0..a3 contiguous? not guaranteed; copy
    float buf[16];
    buf[0]=a0.x; buf[1]=a0.y; buf[2]=a0.z; buf[3]=a0.w;
    buf[4]=a1.x; buf[5]=a1.y; buf[6]=a1.z; buf[7]=a1.w;
    buf[8]=a2.x; buf[9]=a2.y; buf[10]=a2.z; buf[11]=a2.w;
    buf[12]=a3.x; buf[13]=a3.y; buf[14]=a3.z; buf[15]=a3.w;
    (void)f;
#pragma unroll
    for (int p = 0; p < 8; ++p) u[p] = pack_bf(buf[2*p], buf[2*p+1]);
    unsigned short* dst = xbf + (size_t)row * cD + lane * 16;
    uint4 v0 = make_uint4(u[0], u[1], u[2], u[3]);
    uint4 v1 = make_uint4(u[4], u[5], u[6], u[7]);
    *(uint4*)(dst)     = v0;
    *(uint4*)(dst + 8) = v1;
  }

  for (int g = 0; g < cG; ++g) {
    const float4* wr = (const float4*)(W_ih + (size_t)g * cD + lane * 16);
    float4 w0 = wr[0], w1 = wr[1], w2 = wr[2], w3 = wr[3];
    float4 s;
    s.x = a0.x*w0.x + a1.x*w1.x + a2.x*w2.x + a3.x*w3.x;
    s.y = a0.y*w0.y + a1.y*w1.y + a2.y*w2.y + a3.y*w3.y;
    s.z = a0.z*w0.z + a1.z*w1.z + a2.z*w2.z + a3.z*w3.z;
    s.w = a0.w*w0.w + a1.w*w1.w + a2.w*w2.w + a3.w*w3.w;
    float p = (s.x + s.y) + (s.z + s.w);
#pragma unroll
    for (int off = 32; off >= 1; off >>= 1) p += __shfl_xor(p, off);
    if (lane == 0) xg[(size_t)row * cG + g] = p + b_ih[g] + b_hh[g];
  }
}

// ---------------------------------------------------------------------------
// K2: LSTM scan. One wave per batch; lane j<20 owns hidden unit j (gates
// i,f,g,o). h broadcast via shuffles. Packed-f32 dot products.
// ---------------------------------------------------------------------------
__global__ __launch_bounds__(64) void k2_lstm(
    const float* __restrict__ xg, const float* __restrict__ W_hh,
    float* __restrict__ hbuf)
{
  const int b = blockIdx.x;
  const int j = threadIdx.x;
  const bool act = j < cPE;

  floatx2 wr[4][10];
#pragma unroll
  for (int r = 0; r < 4; ++r)
#pragma unroll
    for (int p = 0; p < 10; ++p) {
      float w0 = act ? W_hh[(r*cPE + j)*cPE + 2*p]     : 0.f;
      float w1 = act ? W_hh[(r*cPE + j)*cPE + 2*p + 1] : 0.f;
      floatx2 t; t.x = w0; t.y = w1; wr[r][p] = t;
    }

  floatx2 hv[10];
#pragma unroll
  for (int p = 0; p < 10; ++p) { hv[p].x = 0.f; hv[p].y = 0.f; }
  float c = 0.f;

  const float* xb = xg + (size_t)b * cS * cG;
  float pf[4][4];
#pragma unroll
  for (int q = 0; q < 4; ++q)
#pragma unroll
    for (int r = 0; r < 4; ++r)
      pf[q][r] = act ? xb[q*cG + r*cPE + j] : 0.f;

#pragma unroll 4
  for (int t = 0; t < cS; ++t) {
    const int q = t & 3;
    floatx2 a0, a1, a2, a3;
    a0.x = pf[q][0]; a0.y = 0.f;
    a1.x = pf[q][1]; a1.y = 0.f;
    a2.x = pf[q][2]; a2.y = 0.f;
    a3.x = pf[q][3]; a3.y = 0.f;
#pragma unroll
    for (int p = 0; p < 10; ++p) {
      a0 += wr[0][p] * hv[p];
      a1 += wr[1][p] * hv[p];
      a2 += wr[2][p] * hv[p];
      a3 += wr[3][p] * hv[p];
    }
    if (t + 4 < cS) {
#pragma unroll
      for (int r = 0; r < 4; ++r)
        pf[q][r] = act ? xb[(t+4)*cG + r*cPE + j] : 0.f;
    }
    float gi = a0.x + a0.y, gf = a1.x + a1.y;
    float gg = a2.x + a2.y, go = a3.x + a3.y;
    c = fsig(gf) * c + fsig(gi) * ftanh(gg);
    float hj = fsig(go) * ftanh(c);
    if (act) hbuf[((size_t)b * cS + t) * cPE + j] = hj;
#pragma unroll
    for (int p = 0; p < 10; ++p) {
      floatx2 nh;
      nh.x = __shfl(hj, 2*p);
      nh.y = __shfl(hj, 2*p + 1);
      hv[p] = nh;
    }
  }
}

// ---------------------------------------------------------------------------
// K3: mu_w = relu(h@W_mu^T + b_mu), sigma = sigmoid(h@W_sig^T + b_sig),
// then the sequential mu recurrence (16 independent chains).
// Single block of 256 threads.
// ---------------------------------------------------------------------------
__global__ __launch_bounds__(256) void k3_mu(
    const float* __restrict__ hbuf,
    const float* __restrict__ W_mu, const float* __restrict__ b_mu,
    const float* __restrict__ W_sig, const float* __restrict__ b_sig,
    float* __restrict__ muw, float* __restrict__ sigma, float* __restrict__ mu)
{
  __shared__ float sw[84];
  const int t = threadIdx.x;
  if (t < 60) sw[t] = W_mu[t];
  else if (t < 80) sw[t] = W_sig[t - 60];
  else if (t < 83) sw[t] = b_mu[t - 80];
  else if (t == 83) sw[t] = b_sig[0];
  __syncthreads();

  for (int r = t; r < cB * cS; r += 256) {
    const float4* hp = (const float4*)(hbuf + (size_t)r * cPE);
    float h[20];
#pragma unroll
    for (int q2 = 0; q2 < 5; ++q2) {
      float4 v = hp[q2];
      h[4*q2] = v.x; h[4*q2+1] = v.y; h[4*q2+2] = v.z; h[4*q2+3] = v.w;
    }
    float m0 = sw[80], m1 = sw[81], m2 = sw[82], sg = sw[83];
#pragma unroll
    for (int p = 0; p < 20; ++p) {
      m0 += sw[p]      * h[p];
      m1 += sw[20 + p] * h[p];
      m2 += sw[40 + p] * h[p];
      sg += sw[60 + p] * h[p];
    }
    muw[(size_t)r*3 + 0] = fmaxf(m0, 0.f);
    muw[(size_t)r*3 + 1] = fmaxf(m1, 0.f);
    muw[(size_t)r*3 + 2] = fmaxf(m2, 0.f);
    sigma[r] = fsig(sg);
  }
  __syncthreads();

  if (t < cB) {
    const float* base = muw + (size_t)t * cS * 3;
    float pf[8][3];
#pragma unroll
    for (int q = 0; q < 8; ++q) {
      pf[q][0] = base[q*3]; pf[q][1] = base[q*3+1]; pf[q][2] = base[q*3+2];
    }
    float m = 0.f;
    float* mb = mu + (size_t)t * cS;
    const float inv = 1.f / (float)cS;
#pragma unroll 8
    for (int tt = 0; tt < cS; ++tt) {
      const int q = tt & 7;
      float w0 = pf[q][0], w1 = pf[q][1], w2 = pf[q][2];
      if (tt + 8 < cS) {
        pf[q][0] = base[(tt+8)*3];
        pf[q][1] = base[(tt+8)*3 + 1];
        pf[q][2] = base[(tt+8)*3 + 2];
      }
      m = w0 * m + w1 * inv + w2 * (float)(tt + 1) * inv;
      mb[tt] = m;
    }
  }
}

// ---------------------------------------------------------------------------
// K4: fused positional attention.
// context[b,j,:] = (sum_{i<=j} w_ji * x[b,i,:]) / max(||w_j||_2, 1e-12)
// w generated on the fly in MFMA A-fragment layout; x staged to LDS as bf16.
// Block: 256 thr = 4 waves, tile 64(j) x 128(d); K-step 32 over i.
// ---------------------------------------------------------------------------
static constexpr int TJ = 64, TD = 128, KI = 32, XSTR = 130;

__global__ __launch_bounds__(256) void k4_attn(
    const float* __restrict__ x, const unsigned short* __restrict__ xbf,
    int use_bf, const float* __restrict__ mu, const float* __restrict__ sigma,
    float* __restrict__ out)
{
  __shared__ unsigned short xs[KI * XSTR];
  __shared__ float snrm[4][16];

  const int b   = blockIdx.z;
  const int jt0 = blockIdx.x * TJ;
  const int dt0 = blockIdx.y * TD;
  const int tid = threadIdx.x;
  const int wave = tid >> 6, lane = tid & 63;
  const int m = lane & 15, quad = lane >> 4;
  const int jrow = jt0 + wave * 16 + m;

  const float muv  = mu[b * cS + jrow];
  const float sg   = sigma[b * cS + jrow];
  const float invj = 1.f / (float)(jrow + 1);
  const float ce   = -0.72134752f / (sg * sg);   // -log2(e)/(2*sigma^2)

  float nrm2 = 0.f;
  floatx4 acc[8];
#pragma unroll
  for (int nt = 0; nt < 8; ++nt) acc[nt] = (floatx4)0.f;

  const int iend = jt0 + TJ;
  for (int i0 = 0; i0 < iend; i0 += KI) {
    __syncthreads();
    // ---- stage x[i0..i0+31, dt0..dt0+127] as bf16 into LDS (row-major i) ---
#pragma unroll
    for (int cc = 0; cc < 2; ++cc) {
      const int c   = tid + cc * 256;
      const int il  = c >> 4;        // 0..31
      const int dch = c & 15;        // 0..15 (8 d's each)
      uint4 v;
      if (use_bf) {
        v = *(const uint4*)(xbf + ((size_t)b*cS + i0 + il)*cD + dt0 + dch*8);
      } else {
        const float* xp = x + ((size_t)b*cS + i0 + il)*cD + dt0 + dch*8;
        float4 f0 = *(const float4*)xp;
        float4 f1 = *(const float4*)(xp + 4);
        v.x = pack_bf(f0.x, f0.y); v.y = pack_bf(f0.z, f0.w);
        v.z = pack_bf(f1.x, f1.y); v.w = pack_bf(f1.z, f1.w);
      }
      unsigned* wp = (unsigned*)(xs + il * XSTR + dch * 8);
      wp[0] = v.x; wp[1] = v.y; wp[2] = v.z; wp[3] = v.w;
    }
    __syncthreads();

    // ---- A fragment: w values for (j=jrow, i = i0 + quad*8 + e) -----------
    short8 af;
    const float base = (float)(i0 + quad * 8) * invj - muv;
#pragma unroll
    for (int e = 0; e < 8; ++e) {
      const int ig = i0 + quad * 8 + e;
      float d = fmaf((float)e, invj, base);
      float w = exp2f(d * d * ce);
      w = (ig <= jrow) ? w : 0.f;
      nrm2 += w * w;
      union { float f; unsigned u; } cv; cv.f = w;
      af[e] = (short)(cv.u >> 16);
    }

    // ---- B fragments from LDS + MFMA --------------------------------------
#pragma unroll
    for (int nt = 0; nt < 8; ++nt) {
      short8 bf;
#pragma unroll
      for (int e = 0; e < 8; ++e)
        bf[e] = (short)xs[(quad * 8 + e) * XSTR + nt * 16 + m];
      acc[nt] = __builtin_amdgcn_mfma_f32_16x16x32_bf16(af, bf, acc[nt], 0, 0, 0);
    }
  }

  // ---- norm reduction + epilogue ------------------------------------------
  nrm2 += __shfl_xor(nrm2, 16);
  nrm2 += __shfl_xor(nrm2, 32);
  if (quad == 0) snrm[wave][m] = nrm2;
  __syncthreads();

  float scl[4];
#pragma unroll
  for (int r = 0; r < 4; ++r) {
    float nr = snrm[wave][quad * 4 + r];
    scl[r] = __builtin_amdgcn_rcpf(fmaxf(sqrtf(nr), 1e-12f));
  }
#pragma unroll
  for (int nt = 0; nt < 8; ++nt)
#pragma unroll
    for (int r = 0; r < 4; ++r) {
      const int j = jt0 + wave * 16 + quad * 4 + r;
      out[((size_t)b * cS + j) * cD + dt0 + nt * 16 + m] = acc[nt][r] * scl[r];
    }
}

// ---------------------------------------------------------------------------
extern "C" void kernel_launch(void* const* d_in, const int* in_sizes, int n_in,
                              void* d_out, int out_size, void* d_ws, size_t ws_size,
                              hipStream_t stream) {
  const float* x     = (const float*)d_in[0];
  const float* W_ih  = (const float*)d_in[1];
  const float* W_hh  = (const float*)d_in[2];
  const float* b_ih  = (const float*)d_in[3];
  const float* b_hh  = (const float*)d_in[4];
  const float* W_mu  = (const float*)d_in[5];
  const float* b_mu  = (const float*)d_in[6];
  const float* W_sig = (const float*)d_in[7];
  const float* b_sig = (const float*)d_in[8];
  float* out = (float*)d_out;

  char* ws = (char*)d_ws;
  const size_t off_xg  = 0;                                   // 16*1024*80*4
  const size_t off_h   = off_xg  + (size_t)cB*cS*cG*4;        // +5242880
  const size_t off_muw = off_h   + (size_t)cB*cS*cPE*4;       // +1310720
  const size_t off_sig = off_muw + (size_t)cB*cS*3*4;         // +196608
  const size_t off_mu  = off_sig + (size_t)cB*cS*4;           // +65536
  const size_t off_xbf = off_mu  + (size_t)cB*cS*4;           // +65536
  const size_t need_bf = off_xbf + (size_t)cB*cS*cD*2;        // +33554432

  float* xg    = (float*)(ws + off_xg);
  float* hbuf  = (float*)(ws + off_h);
  float* muw   = (float*)(ws + off_muw);
  float* sigma = (float*)(ws + off_sig);
  float* mu    = (float*)(ws + off_mu);
  unsigned short* xbf = (unsigned short*)(ws + off_xbf);
  const int use_bf = (ws_size >= need_bf) ? 1 : 0;

  k1_xg  <<<dim3(cB * cS / 4), dim3(256), 0, stream>>>(x, W_ih, b_ih, b_hh, xg, xbf, use_bf);
  k2_lstm<<<dim3(cB),          dim3(64),  0, stream>>>(xg, W_hh, hbuf);
  k3_mu  <<<dim3(1),           dim3(256), 0, stream>>>(hbuf, W_mu, b_mu, W_sig, b_sig, muw, sigma, mu);
  k4_attn<<<dim3(cS/TJ, cD/TD, cB), dim3(256), 0, stream>>>(x, xbf, use_bf, mu, sigma, out);
}

// Round 2
// 785.658 us; speedup vs baseline: 1.4433x; 1.4433x over previous
//
#include <hip/hip_runtime.h>

#define DEVFN __device__ __forceinline__

static constexpr int cB  = 16;
static constexpr int cS  = 1024;
static constexpr int cD  = 1024;
static constexpr int cPE = 20;
static constexpr int cG  = 80;   // 4*PE

typedef float  floatx2  __attribute__((ext_vector_type(2)));
typedef float  floatx4  __attribute__((ext_vector_type(4)));
typedef float  floatx16 __attribute__((ext_vector_type(16)));
typedef short  short8   __attribute__((ext_vector_type(8)));

DEVFN unsigned pack_bf(float a, float b) {
  union { float f; unsigned u; } ua, ub; ua.f = a; ub.f = b;
  return (ua.u >> 16) | (ub.u & 0xffff0000u);
}

// ---------------------------------------------------------------------------
// K1: xg = x @ W_ih^T + b_ih + b_hh  (fp32, LDS-tiled, 4x5 register blocking)
//     + fused emit of x transposed to bf16: xbf_t[b][d][s]
// Tile: 64 rows x 80 gates, K-chunks of 64. Grid = 256 blocks (1/CU).
// ---------------------------------------------------------------------------
static constexpr int K1_XS = 68;  // LDS row stride (floats)

__global__ __launch_bounds__(256) void k1_xg(
    const float* __restrict__ x, const float* __restrict__ W_ih,
    const float* __restrict__ b_ih, const float* __restrict__ b_hh,
    float* __restrict__ xg, unsigned short* __restrict__ xbf_t, int use_bf)
{
  __shared__ float xs[64 * K1_XS];   // 17408 B
  __shared__ float wsm[80 * K1_XS];  // 21760 B

  const int t  = threadIdx.x;
  const int rg = t >> 4, cg = t & 15;
  const int r0 = rg * 4, c0 = cg * 5;
  const int row0 = blockIdx.x * 64;
  const int b  = row0 >> 10;
  const int s0 = row0 & 1023;

  floatx2 acc[4][5];
#pragma unroll
  for (int q = 0; q < 4; ++q)
#pragma unroll
    for (int cc = 0; cc < 5; ++cc) { acc[q][cc].x = 0.f; acc[q][cc].y = 0.f; }

  for (int kc = 0; kc < 16; ++kc) {
    const int k0 = kc * 64;
    // ---- stage x tile: 64 rows x 64 k ------------------------------------
    {
      const int sr = t >> 2, sc = t & 3;
      const float4* src = (const float4*)(x + (size_t)(row0 + sr) * cD + k0 + sc * 16);
      float4 v0 = src[0], v1 = src[1], v2 = src[2], v3 = src[3];
      float4* dst = (float4*)&xs[sr * K1_XS + sc * 16];
      dst[0] = v0; dst[1] = v1; dst[2] = v2; dst[3] = v3;
    }
    // ---- stage W tile: 80 gates x 64 k -----------------------------------
#pragma unroll
    for (int q = 0; q < 5; ++q) {
      const int id = t + q * 256;          // 0..1279
      const int g = id >> 4, c4 = id & 15;
      float4 wv = *(const float4*)(W_ih + (size_t)g * cD + k0 + c4 * 4);
      *(float4*)&wsm[g * K1_XS + c4 * 4] = wv;
    }
    __syncthreads();

    // ---- transposed bf16 emit: xbf_t[b][k0+dl][s0 + 16*sc4 + e] ----------
    if (use_bf) {
      const int dl = t >> 2, sc4 = t & 3;
      float v[16];
#pragma unroll
      for (int e = 0; e < 16; ++e) v[e] = xs[(sc4 * 16 + e) * K1_XS + dl];
      unsigned u[8];
#pragma unroll
      for (int p = 0; p < 8; ++p) u[p] = pack_bf(v[2 * p], v[2 * p + 1]);
      unsigned short* dstp = xbf_t + ((size_t)(b * cD + k0 + dl)) * cS + s0 + sc4 * 16;
      *(uint4*)dstp       = make_uint4(u[0], u[1], u[2], u[3]);
      *(uint4*)(dstp + 8) = make_uint4(u[4], u[5], u[6], u[7]);
    }

    // ---- compute: 32 x (9 ds_read_b64 + 20 pk_fma) -----------------------
#pragma unroll 4
    for (int k2 = 0; k2 < 32; ++k2) {
      floatx2 xv[4], wv[5];
#pragma unroll
      for (int q = 0; q < 4; ++q)
        xv[q] = *(const floatx2*)&xs[(r0 + q) * K1_XS + 2 * k2];
#pragma unroll
      for (int cc = 0; cc < 5; ++cc)
        wv[cc] = *(const floatx2*)&wsm[(c0 + cc) * K1_XS + 2 * k2];
#pragma unroll
      for (int q = 0; q < 4; ++q)
#pragma unroll
        for (int cc = 0; cc < 5; ++cc)
          acc[q][cc] += xv[q] * wv[cc];
    }
    __syncthreads();
  }

  float bsum[5];
#pragma unroll
  for (int cc = 0; cc < 5; ++cc) bsum[cc] = b_ih[c0 + cc] + b_hh[c0 + cc];
#pragma unroll
  for (int q = 0; q < 4; ++q)
#pragma unroll
    for (int cc = 0; cc < 5; ++cc)
      xg[(size_t)(row0 + r0 + q) * cG + c0 + cc] = acc[q][cc].x + acc[q][cc].y + bsum[cc];
}

// ---------------------------------------------------------------------------
// K2: LSTM scan. One wave per batch; lane j owns unit j (lanes >=20 mirror
// lane 19). Gate weights pre-scaled by log2(e) so activations are raw
// v_exp_f32 + v_rcp_f32. h broadcast via v_readlane (no LDS).
// ---------------------------------------------------------------------------
__global__ __launch_bounds__(64) void k2_lstm(
    const float* __restrict__ xg, const float* __restrict__ W_hh,
    float* __restrict__ hbuf)
{
  const int b = blockIdx.x;
  const int j = threadIdx.x;
  const int j19 = j < cPE ? j : cPE - 1;
  const float LOG2E = 1.44269504f, TWOLOG2E = 2.88539008f;
  const float sclr[4] = {LOG2E, LOG2E, TWOLOG2E, LOG2E};

  floatx2 wr[4][10];
#pragma unroll
  for (int r = 0; r < 4; ++r)
#pragma unroll
    for (int p = 0; p < 10; ++p) {
      floatx2 tv;
      tv.x = W_hh[(r * cPE + j19) * cPE + 2 * p]     * sclr[r];
      tv.y = W_hh[(r * cPE + j19) * cPE + 2 * p + 1] * sclr[r];
      wr[r][p] = tv;
    }

  floatx2 hv[10];
#pragma unroll
  for (int p = 0; p < 10; ++p) { hv[p].x = 0.f; hv[p].y = 0.f; }
  float c = 0.f;

  const float* xb = xg + (size_t)b * cS * cG;
  float pf[4][4];
#pragma unroll
  for (int q = 0; q < 4; ++q)
#pragma unroll
    for (int r = 0; r < 4; ++r)
      pf[q][r] = xb[q * cG + r * cPE + j19] * sclr[r];

#pragma unroll 4
  for (int t = 0; t < cS; ++t) {
    const int q = t & 3;
    floatx2 a0, a1, a2, a3;
    a0.x = pf[q][0]; a0.y = 0.f;
    a1.x = pf[q][1]; a1.y = 0.f;
    a2.x = pf[q][2]; a2.y = 0.f;
    a3.x = pf[q][3]; a3.y = 0.f;
#pragma unroll
    for (int p = 0; p < 10; ++p) {
      a0 += wr[0][p] * hv[p];
      a1 += wr[1][p] * hv[p];
      a2 += wr[2][p] * hv[p];
      a3 += wr[3][p] * hv[p];
    }
    if (t + 4 < cS) {
#pragma unroll
      for (int r = 0; r < 4; ++r)
        pf[q][r] = xb[(t + 4) * cG + r * cPE + j19] * sclr[r];
    }
    const float gi = a0.x + a0.y, gf = a1.x + a1.y;
    const float gg = a2.x + a2.y, go = a3.x + a3.y;
    // sigmoid(x) = 1/(1+2^-x'), x' pre-scaled by log2e
    const float si = __builtin_amdgcn_rcpf(1.f + __builtin_amdgcn_exp2f(-gi));
    const float sf = __builtin_amdgcn_rcpf(1.f + __builtin_amdgcn_exp2f(-gf));
    const float so = __builtin_amdgcn_rcpf(1.f + __builtin_amdgcn_exp2f(-go));
    // tanh(g) = (2^g' - 1)/(2^g' + 1), g' pre-scaled by 2*log2e
    const float tt = __builtin_amdgcn_exp2f(fminf(gg, 30.f));
    const float tg = (tt - 1.f) * __builtin_amdgcn_rcpf(tt + 1.f);
    c = sf * c + si * tg;
    const float t2 = __builtin_amdgcn_exp2f(fminf(TWOLOG2E * c, 30.f));
    const float th = (t2 - 1.f) * __builtin_amdgcn_rcpf(t2 + 1.f);
    const float hj = so * th;
    if (j < cPE) hbuf[((size_t)b * cS + t) * cPE + j] = hj;
    const int hb = __float_as_int(hj);
#pragma unroll
    for (int p = 0; p < 10; ++p) {
      floatx2 nh;
      nh.x = __int_as_float(__builtin_amdgcn_readlane(hb, 2 * p));
      nh.y = __int_as_float(__builtin_amdgcn_readlane(hb, 2 * p + 1));
      hv[p] = nh;
    }
  }
}

// ---------------------------------------------------------------------------
// K3a: muwT[g][r] = relu(h@W_mu^T + b_mu), sigma = sigmoid(h@W_sig^T + b_sig)
// SoA output for the scan kernel. Grid: 64 blocks x 256.
// ---------------------------------------------------------------------------
__global__ __launch_bounds__(256) void k3a_muw(
    const float* __restrict__ hbuf,
    const float* __restrict__ W_mu, const float* __restrict__ b_mu,
    const float* __restrict__ W_sig, const float* __restrict__ b_sig,
    float* __restrict__ muwT, float* __restrict__ sigma)
{
  __shared__ float sw[84];
  const int t = threadIdx.x;
  if (t < 60) sw[t] = W_mu[t];
  else if (t < 80) sw[t] = W_sig[t - 60];
  else if (t < 83) sw[t] = b_mu[t - 80];
  else if (t == 83) sw[t] = b_sig[0];
  __syncthreads();

  const int r = blockIdx.x * 256 + t;
  const float4* hp = (const float4*)(hbuf + (size_t)r * cPE);
  float h[20];
#pragma unroll
  for (int q2 = 0; q2 < 5; ++q2) {
    float4 v = hp[q2];
    h[4 * q2] = v.x; h[4 * q2 + 1] = v.y; h[4 * q2 + 2] = v.z; h[4 * q2 + 3] = v.w;
  }
  float m0 = sw[80], m1 = sw[81], m2 = sw[82], sg = sw[83];
#pragma unroll
  for (int p = 0; p < 20; ++p) {
    m0 += sw[p]      * h[p];
    m1 += sw[20 + p] * h[p];
    m2 += sw[40 + p] * h[p];
    sg += sw[60 + p] * h[p];
  }
  muwT[r]                 = fmaxf(m0, 0.f);
  muwT[cB * cS + r]       = fmaxf(m1, 0.f);
  muwT[2 * cB * cS + r]   = fmaxf(m2, 0.f);
  sigma[r] = __builtin_amdgcn_rcpf(1.f + __builtin_amdgcn_exp2f(-1.44269504f * sg));
}

// ---------------------------------------------------------------------------
// K3b: sequential mu recurrence, 16 chains (one lane each), float4 prefetch.
// ---------------------------------------------------------------------------
__global__ __launch_bounds__(64) void k3b_mu(
    const float* __restrict__ muwT, float* __restrict__ mu)
{
  const int t = threadIdx.x;
  if (t >= cB) return;
  const float* s0p = muwT + (size_t)t * cS;
  const float* s1p = muwT + cB * cS + (size_t)t * cS;
  const float* s2p = muwT + 2 * cB * cS + (size_t)t * cS;
  float* mb = mu + (size_t)t * cS;
  const float inv = 1.f / (float)cS;

  float4 a0 = *(const float4*)(s0p);
  float4 a1 = *(const float4*)(s1p);
  float4 a2 = *(const float4*)(s2p);
  float4 n0 = *(const float4*)(s0p + 4);
  float4 n1 = *(const float4*)(s1p + 4);
  float4 n2 = *(const float4*)(s2p + 4);

  float m = 0.f;
  for (int t4 = 0; t4 < 256; ++t4) {
    float4 w0 = a0, w1 = a1, w2 = a2;
    a0 = n0; a1 = n1; a2 = n2;
    if (t4 < 254) {
      n0 = *(const float4*)(s0p + t4 * 4 + 8);
      n1 = *(const float4*)(s1p + t4 * 4 + 8);
      n2 = *(const float4*)(s2p + t4 * 4 + 8);
    }
    const int tt = t4 * 4;
    m = w0.x * m + (w1.x + w2.x * (float)(tt + 1)) * inv; mb[tt]     = m;
    m = w0.y * m + (w1.y + w2.y * (float)(tt + 2)) * inv; mb[tt + 1] = m;
    m = w0.z * m + (w1.z + w2.z * (float)(tt + 3)) * inv; mb[tt + 2] = m;
    m = w0.w * m + (w1.w + w2.w * (float)(tt + 4)) * inv; mb[tt + 3] = m;
  }
}

// ---------------------------------------------------------------------------
// K4: fused positional attention with 32x32x16 bf16 MFMA.
// context[b,j,:] = (sum_{i<=j} w_ji * x[b,i,:]) / max(||w_j||, 1e-12)
// x staged d-major in LDS (from xbf_t) so each B-fragment is one
// ds_read_b128. w generated on the fly in MFMA A-fragment layout.
// Block 256 thr = 4 waves: wave = (jh, dh); tile 64 j x 128 d; K-step 32 i.
// ---------------------------------------------------------------------------
static constexpr int TJ = 64, TD = 128, KI = 32, RS = 40;  // RS: LDS row stride (shorts)

__global__ __launch_bounds__(256) void k4_attn(
    const float* __restrict__ x, const unsigned short* __restrict__ xbf_t,
    int use_bf, const float* __restrict__ mu, const float* __restrict__ sigma,
    float* __restrict__ out)
{
  __shared__ unsigned short xsT[TD * RS];   // 10240 B
  __shared__ float snrm[2][32];
  __shared__ float sscl[2][32];

  const int b   = blockIdx.z;
  const int jt0 = blockIdx.x * TJ;
  const int dt0 = blockIdx.y * TD;
  const int tid = threadIdx.x;
  const int wave = tid >> 6, lane = tid & 63;
  const int jh = wave & 1, dh = wave >> 1;
  const int n32 = lane & 31, half = lane >> 5;
  const int jrow = jt0 + jh * 32 + n32;

  const float muv  = mu[b * cS + jrow];
  const float sg   = sigma[b * cS + jrow];
  const float invj = 1.f / (float)(jrow + 1);
  const float ce   = -0.72134752f / (sg * sg);   // -log2(e)/(2*sigma^2)

  float nrm2 = 0.f;
  floatx16 acc0 = (floatx16)0.f, acc1 = (floatx16)0.f;

  const int iend = jt0 + TJ;
  for (int i0 = 0; i0 < iend; i0 += KI) {
    __syncthreads();
    // ---- stage xsT[d][i] : 128 d-rows x 32 i (bf16) ----------------------
    if (use_bf) {
#pragma unroll
      for (int q = 0; q < 2; ++q) {
        const int cc = tid + q * 256;
        const int dl = cc >> 2, part = cc & 3;
        uint4 v = *(const uint4*)(xbf_t + ((size_t)(b * cD + dt0 + dl)) * cS + i0 + part * 8);
        *(uint4*)&xsT[dl * RS + part * 8] = v;
      }
    } else {
#pragma unroll
      for (int q = 0; q < 2; ++q) {
        const int cc = tid + q * 256;
        const int i = cc & 31, d8 = cc >> 5;
        const float* xp = x + ((size_t)(b * cS + i0 + i)) * cD + dt0 + d8 * 8;
        float4 f0 = *(const float4*)xp;
        float4 f1 = *(const float4*)(xp + 4);
        float vv[8] = {f0.x, f0.y, f0.z, f0.w, f1.x, f1.y, f1.z, f1.w};
#pragma unroll
        for (int e = 0; e < 8; ++e) {
          union { float f; unsigned u; } cv; cv.f = vv[e];
          xsT[(d8 * 8 + e) * RS + i] = (unsigned short)(cv.u >> 16);
        }
      }
    }
    __syncthreads();

    // ---- A fragments (w values), kc = 0,1 --------------------------------
    short8 af0, af1;
#pragma unroll
    for (int kc = 0; kc < 2; ++kc) {
      short8 af;
#pragma unroll
      for (int e = 0; e < 8; ++e) {
        const int ig = i0 + kc * 16 + half * 8 + e;
        const float d = fmaf((float)ig, invj, -muv);
        float w = __builtin_amdgcn_exp2f(ce * d * d);
        w = (ig <= jrow) ? w : 0.f;
        nrm2 += w * w;
        union { float f; unsigned u; } cv; cv.f = w;
        af[e] = (short)(cv.u >> 16);
      }
      if (kc == 0) af0 = af; else af1 = af;
    }

    // ---- B fragments (one ds_read_b128 each) + MFMA ----------------------
    const int rbase = dh * 64 + n32;
    short8 b00 = *(const short8*)&xsT[(rbase)      * RS + half * 8];
    short8 b01 = *(const short8*)&xsT[(rbase)      * RS + 16 + half * 8];
    short8 b10 = *(const short8*)&xsT[(rbase + 32) * RS + half * 8];
    short8 b11 = *(const short8*)&xsT[(rbase + 32) * RS + 16 + half * 8];
    acc0 = __builtin_amdgcn_mfma_f32_32x32x16_bf16(af0, b00, acc0, 0, 0, 0);
    acc0 = __builtin_amdgcn_mfma_f32_32x32x16_bf16(af1, b01, acc0, 0, 0, 0);
    acc1 = __builtin_amdgcn_mfma_f32_32x32x16_bf16(af0, b10, acc1, 0, 0, 0);
    acc1 = __builtin_amdgcn_mfma_f32_32x32x16_bf16(af1, b11, acc1, 0, 0, 0);
  }

  // ---- norms --------------------------------------------------------------
  nrm2 += __shfl_xor(nrm2, 32);
  if (wave < 2 && half == 0) snrm[jh][n32] = nrm2;
  __syncthreads();
  if (tid < 64)
    sscl[tid >> 5][tid & 31] =
        __builtin_amdgcn_rcpf(fmaxf(sqrtf(snrm[tid >> 5][tid & 31]), 1e-12f));
  __syncthreads();

  float srow[16];
#pragma unroll
  for (int reg = 0; reg < 16; ++reg) {
    const int row = (reg & 3) + 8 * (reg >> 2) + 4 * half;
    srow[reg] = sscl[jh][row];
  }
#pragma unroll
  for (int reg = 0; reg < 16; ++reg) {
    const int row = (reg & 3) + 8 * (reg >> 2) + 4 * half;
    const int jg = jt0 + jh * 32 + row;
    const int d0 = dt0 + dh * 64 + n32;
    out[((size_t)(b * cS + jg)) * cD + d0]      = acc0[reg] * srow[reg];
    out[((size_t)(b * cS + jg)) * cD + d0 + 32] = acc1[reg] * srow[reg];
  }
}

// ---------------------------------------------------------------------------
extern "C" void kernel_launch(void* const* d_in, const int* in_sizes, int n_in,
                              void* d_out, int out_size, void* d_ws, size_t ws_size,
                              hipStream_t stream) {
  const float* x     = (const float*)d_in[0];
  const float* W_ih  = (const float*)d_in[1];
  const float* W_hh  = (const float*)d_in[2];
  const float* b_ih  = (const float*)d_in[3];
  const float* b_hh  = (const float*)d_in[4];
  const float* W_mu  = (const float*)d_in[5];
  const float* b_mu  = (const float*)d_in[6];
  const float* W_sig = (const float*)d_in[7];
  const float* b_sig = (const float*)d_in[8];
  float* out = (float*)d_out;

  char* ws = (char*)d_ws;
  const size_t off_xg  = 0;                                   // 16*1024*80*4
  const size_t off_h   = off_xg  + (size_t)cB*cS*cG*4;
  const size_t off_muw = off_h   + (size_t)cB*cS*cPE*4;
  const size_t off_sig = off_muw + (size_t)cB*cS*3*4;
  const size_t off_mu  = off_sig + (size_t)cB*cS*4;
  const size_t off_xbf = off_mu  + (size_t)cB*cS*4;
  const size_t need_bf = off_xbf + (size_t)cB*cS*cD*2;

  float* xg    = (float*)(ws + off_xg);
  float* hbuf  = (float*)(ws + off_h);
  float* muwT  = (float*)(ws + off_muw);
  float* sigma = (float*)(ws + off_sig);
  float* mu    = (float*)(ws + off_mu);
  unsigned short* xbf_t = (unsigned short*)(ws + off_xbf);
  const int use_bf = (ws_size >= need_bf) ? 1 : 0;

  k1_xg  <<<dim3(cB * cS / 64), dim3(256), 0, stream>>>(x, W_ih, b_ih, b_hh, xg, xbf_t, use_bf);
  k2_lstm<<<dim3(cB),           dim3(64),  0, stream>>>(xg, W_hh, hbuf);
  k3a_muw<<<dim3(cB * cS / 256), dim3(256), 0, stream>>>(hbuf, W_mu, b_mu, W_sig, b_sig, muwT, sigma);
  k3b_mu <<<dim3(1),            dim3(64),  0, stream>>>(muwT, mu);
  k4_attn<<<dim3(cS/TJ, cD/TD, cB), dim3(256), 0, stream>>>(x, xbf_t, use_bf, mu, sigma, out);
}

// Round 3
// 594.162 us; speedup vs baseline: 1.9085x; 1.3223x over previous
//
#include <hip/hip_runtime.h>

#define DEVFN __device__ __forceinline__

static constexpr int cB  = 16;
static constexpr int cS  = 1024;
static constexpr int cD  = 1024;
static constexpr int cPE = 20;
static constexpr int cG  = 80;   // 4*PE

typedef float  floatx2  __attribute__((ext_vector_type(2)));
typedef float  floatx4  __attribute__((ext_vector_type(4)));
typedef float  floatx16 __attribute__((ext_vector_type(16)));
typedef short  short8   __attribute__((ext_vector_type(8)));

DEVFN unsigned pack_bf(float a, float b) {
  union { float f; unsigned u; } ua, ub; ua.f = a; ub.f = b;
  return (ua.u >> 16) | (ub.u & 0xffff0000u);
}

// ---------------------------------------------------------------------------
// K1: xgT[b][g][t] = (x @ W_ih^T + b_ih + b_hh) * gate_scale(g), transposed
//     for k2's streaming loads. gate_scale = 2*log2e for g in [40,60) (the
//     tanh gate), log2e otherwise.
//     + fused emit of x transposed to bf16: xbf_t[b][d][s] for k4.
// Tile: 64 rows x 80 gates, K-chunks of 64. Grid = 256 blocks.
// ---------------------------------------------------------------------------
static constexpr int K1_XS = 68;  // LDS row stride (floats)

__global__ __launch_bounds__(256) void k1_xg(
    const float* __restrict__ x, const float* __restrict__ W_ih,
    const float* __restrict__ b_ih, const float* __restrict__ b_hh,
    float* __restrict__ xgT, unsigned short* __restrict__ xbf_t, int use_bf)
{
  __shared__ float xs[64 * K1_XS];   // 17408 B
  __shared__ float wsm[80 * K1_XS];  // 21760 B

  const int t  = threadIdx.x;
  const int rg = t >> 4, cg = t & 15;
  const int r0 = rg * 4, c0 = cg * 5;
  const int row0 = blockIdx.x * 64;
  const int b  = row0 >> 10;
  const int s0 = row0 & 1023;

  floatx2 acc[4][5];
#pragma unroll
  for (int q = 0; q < 4; ++q)
#pragma unroll
    for (int cc = 0; cc < 5; ++cc) { acc[q][cc].x = 0.f; acc[q][cc].y = 0.f; }

  for (int kc = 0; kc < 16; ++kc) {
    const int k0 = kc * 64;
    // ---- stage x tile: 64 rows x 64 k ------------------------------------
    {
      const int sr = t >> 2, sc = t & 3;
      const float4* src = (const float4*)(x + (size_t)(row0 + sr) * cD + k0 + sc * 16);
      float4 v0 = src[0], v1 = src[1], v2 = src[2], v3 = src[3];
      float4* dst = (float4*)&xs[sr * K1_XS + sc * 16];
      dst[0] = v0; dst[1] = v1; dst[2] = v2; dst[3] = v3;
    }
    // ---- stage W tile: 80 gates x 64 k -----------------------------------
#pragma unroll
    for (int q = 0; q < 5; ++q) {
      const int id = t + q * 256;          // 0..1279
      const int g = id >> 4, c4 = id & 15;
      float4 wv = *(const float4*)(W_ih + (size_t)g * cD + k0 + c4 * 4);
      *(float4*)&wsm[g * K1_XS + c4 * 4] = wv;
    }
    __syncthreads();

    // ---- transposed bf16 emit: xbf_t[b][k0+dl][s0 + 16*sc4 + e] ----------
    if (use_bf) {
      const int dl = t >> 2, sc4 = t & 3;
      float v[16];
#pragma unroll
      for (int e = 0; e < 16; ++e) v[e] = xs[(sc4 * 16 + e) * K1_XS + dl];
      unsigned u[8];
#pragma unroll
      for (int p = 0; p < 8; ++p) u[p] = pack_bf(v[2 * p], v[2 * p + 1]);
      unsigned short* dstp = xbf_t + ((size_t)(b * cD + k0 + dl)) * cS + s0 + sc4 * 16;
      *(uint4*)dstp       = make_uint4(u[0], u[1], u[2], u[3]);
      *(uint4*)(dstp + 8) = make_uint4(u[4], u[5], u[6], u[7]);
    }

    // ---- compute: 32 x (9 ds_read_b64 + 20 pk_fma) -----------------------
#pragma unroll 4
    for (int k2 = 0; k2 < 32; ++k2) {
      floatx2 xv[4], wv[5];
#pragma unroll
      for (int q = 0; q < 4; ++q)
        xv[q] = *(const floatx2*)&xs[(r0 + q) * K1_XS + 2 * k2];
#pragma unroll
      for (int cc = 0; cc < 5; ++cc)
        wv[cc] = *(const floatx2*)&wsm[(c0 + cc) * K1_XS + 2 * k2];
#pragma unroll
      for (int q = 0; q < 4; ++q)
#pragma unroll
        for (int cc = 0; cc < 5; ++cc)
          acc[q][cc] += xv[q] * wv[cc];
    }
    __syncthreads();
  }

  // ---- epilogue: scaled, biased, transposed stores (float4 over t) -------
#pragma unroll
  for (int cc = 0; cc < 5; ++cc) {
    const int g = c0 + cc;
    const float sc = (g >= 40 && g < 60) ? 2.88539008f : 1.44269504f;
    const float bs = b_ih[g] + b_hh[g];
    float4 v;
    v.x = (acc[0][cc].x + acc[0][cc].y + bs) * sc;
    v.y = (acc[1][cc].x + acc[1][cc].y + bs) * sc;
    v.z = (acc[2][cc].x + acc[2][cc].y + bs) * sc;
    v.w = (acc[3][cc].x + acc[3][cc].y + bs) * sc;
    *(float4*)&xgT[((size_t)(b * cG + g)) * cS + s0 + r0] = v;
  }
}

// ---------------------------------------------------------------------------
// K2: LSTM scan. One wave per batch; lane j owns unit j (lanes >=20 mirror
// lane 19). xgT is pre-scaled + biased; 4 contiguous float4 streams per lane
// with 4-slot rotation => 16 loads in flight, 16-step prefetch distance.
// h broadcast via __shfl (ds_bpermute). Dots: two depth-5 pk_fma chains.
// ---------------------------------------------------------------------------
__global__ __launch_bounds__(64) void k2_lstm(
    const float* __restrict__ xgT, const float* __restrict__ W_hh,
    float* __restrict__ hbuf)
{
  const int b = blockIdx.x;
  const int j = threadIdx.x;
  const int j19 = j < cPE ? j : cPE - 1;
  const float LOG2E = 1.44269504f, TWOLOG2E = 2.88539008f;
  const float sclr[4] = {LOG2E, LOG2E, TWOLOG2E, LOG2E};

  floatx2 wr[4][10];
#pragma unroll
  for (int r = 0; r < 4; ++r)
#pragma unroll
    for (int p = 0; p < 10; ++p) {
      floatx2 tv;
      tv.x = W_hh[(r * cPE + j19) * cPE + 2 * p]     * sclr[r];
      tv.y = W_hh[(r * cPE + j19) * cPE + 2 * p + 1] * sclr[r];
      wr[r][p] = tv;
    }

  const float* base[4];
#pragma unroll
  for (int r = 0; r < 4; ++r)
    base[r] = xgT + ((size_t)(b * cG + r * cPE + j19)) * cS;

  // 4-slot rotation, slot s holds quad (T + s); prefetch writes quad T+s+4.
  // Trailing prefetches read up to 64B past xgT's end -> lands in hbuf
  // region of d_ws (allocated, unused garbage) - safe.
  float4 buf[4][4];
#pragma unroll
  for (int s = 0; s < 4; ++s)
#pragma unroll
    for (int r = 0; r < 4; ++r)
      buf[s][r] = *(const float4*)(base[r] + s * 4);

  floatx2 hv[10];
#pragma unroll
  for (int p = 0; p < 10; ++p) { hv[p].x = 0.f; hv[p].y = 0.f; }
  float c = 0.f;

  for (int T = 0; T < 256; T += 4) {
#pragma unroll
    for (int s = 0; s < 4; ++s) {
      float4 g4[4];
#pragma unroll
      for (int r = 0; r < 4; ++r) {
        g4[r] = buf[s][r];
        buf[s][r] = *(const float4*)(base[r] + (T + s + 4) * 4);
      }
#pragma unroll
      for (int e = 0; e < 4; ++e) {
        const float ge0 = (e == 0) ? g4[0].x : (e == 1) ? g4[0].y : (e == 2) ? g4[0].z : g4[0].w;
        const float ge1 = (e == 0) ? g4[1].x : (e == 1) ? g4[1].y : (e == 2) ? g4[1].z : g4[1].w;
        const float ge2 = (e == 0) ? g4[2].x : (e == 1) ? g4[2].y : (e == 2) ? g4[2].z : g4[2].w;
        const float ge3 = (e == 0) ? g4[3].x : (e == 1) ? g4[3].y : (e == 2) ? g4[3].z : g4[3].w;
        floatx2 a0l, a0h, a1l, a1h, a2l, a2h, a3l, a3h;
        a0l.x = ge0; a0l.y = 0.f; a0h.x = 0.f; a0h.y = 0.f;
        a1l.x = ge1; a1l.y = 0.f; a1h.x = 0.f; a1h.y = 0.f;
        a2l.x = ge2; a2l.y = 0.f; a2h.x = 0.f; a2h.y = 0.f;
        a3l.x = ge3; a3l.y = 0.f; a3h.x = 0.f; a3h.y = 0.f;
#pragma unroll
        for (int p = 0; p < 5; ++p) {
          a0l += wr[0][p] * hv[p];
          a1l += wr[1][p] * hv[p];
          a2l += wr[2][p] * hv[p];
          a3l += wr[3][p] * hv[p];
        }
#pragma unroll
        for (int p = 5; p < 10; ++p) {
          a0h += wr[0][p] * hv[p];
          a1h += wr[1][p] * hv[p];
          a2h += wr[2][p] * hv[p];
          a3h += wr[3][p] * hv[p];
        }
        const float gi = (a0l.x + a0l.y) + (a0h.x + a0h.y);
        const float gf = (a1l.x + a1l.y) + (a1h.x + a1h.y);
        const float gg = (a2l.x + a2l.y) + (a2h.x + a2h.y);
        const float go = (a3l.x + a3l.y) + (a3h.x + a3h.y);
        const float si = __builtin_amdgcn_rcpf(1.f + __builtin_amdgcn_exp2f(-gi));
        const float sf = __builtin_amdgcn_rcpf(1.f + __builtin_amdgcn_exp2f(-gf));
        const float so = __builtin_amdgcn_rcpf(1.f + __builtin_amdgcn_exp2f(-go));
        const float tt = __builtin_amdgcn_exp2f(fminf(gg, 30.f));
        const float tg = (tt - 1.f) * __builtin_amdgcn_rcpf(tt + 1.f);
        c = sf * c + si * tg;
        const float t2 = __builtin_amdgcn_exp2f(fminf(TWOLOG2E * c, 30.f));
        const float th = (t2 - 1.f) * __builtin_amdgcn_rcpf(t2 + 1.f);
        const float hj = so * th;
        if (j < cPE) hbuf[((size_t)b * cS + (T + s) * 4 + e) * cPE + j] = hj;
#pragma unroll
        for (int p = 0; p < 10; ++p) {
          floatx2 nh;
          nh.x = __shfl(hj, 2 * p);
          nh.y = __shfl(hj, 2 * p + 1);
          hv[p] = nh;
        }
      }
    }
  }
}

// ---------------------------------------------------------------------------
// K3a: muwT[g][r] = relu(h@W_mu^T + b_mu), sigma = sigmoid(h@W_sig^T + b_sig)
// SoA output for the scan kernel. Grid: 64 blocks x 256.
// ---------------------------------------------------------------------------
__global__ __launch_bounds__(256) void k3a_muw(
    const float* __restrict__ hbuf,
    const float* __restrict__ W_mu, const float* __restrict__ b_mu,
    const float* __restrict__ W_sig, const float* __restrict__ b_sig,
    float* __restrict__ muwT, float* __restrict__ sigma)
{
  __shared__ float sw[84];
  const int t = threadIdx.x;
  if (t < 60) sw[t] = W_mu[t];
  else if (t < 80) sw[t] = W_sig[t - 60];
  else if (t < 83) sw[t] = b_mu[t - 80];
  else if (t == 83) sw[t] = b_sig[0];
  __syncthreads();

  const int r = blockIdx.x * 256 + t;
  const float4* hp = (const float4*)(hbuf + (size_t)r * cPE);
  float h[20];
#pragma unroll
  for (int q2 = 0; q2 < 5; ++q2) {
    float4 v = hp[q2];
    h[4 * q2] = v.x; h[4 * q2 + 1] = v.y; h[4 * q2 + 2] = v.z; h[4 * q2 + 3] = v.w;
  }
  float m0 = sw[80], m1 = sw[81], m2 = sw[82], sg = sw[83];
#pragma unroll
  for (int p = 0; p < 20; ++p) {
    m0 += sw[p]      * h[p];
    m1 += sw[20 + p] * h[p];
    m2 += sw[40 + p] * h[p];
    sg += sw[60 + p] * h[p];
  }
  muwT[r]                 = fmaxf(m0, 0.f);
  muwT[cB * cS + r]       = fmaxf(m1, 0.f);
  muwT[2 * cB * cS + r]   = fmaxf(m2, 0.f);
  sigma[r] = __builtin_amdgcn_rcpf(1.f + __builtin_amdgcn_exp2f(-1.44269504f * sg));
}

// ---------------------------------------------------------------------------
// K3b: sequential mu recurrence, 16 chains (one lane each), float4 prefetch.
// ---------------------------------------------------------------------------
__global__ __launch_bounds__(64) void k3b_mu(
    const float* __restrict__ muwT, float* __restrict__ mu)
{
  const int t = threadIdx.x;
  if (t >= cB) return;
  const float* s0p = muwT + (size_t)t * cS;
  const float* s1p = muwT + cB * cS + (size_t)t * cS;
  const float* s2p = muwT + 2 * cB * cS + (size_t)t * cS;
  float* mb = mu + (size_t)t * cS;
  const float inv = 1.f / (float)cS;

  float4 a0 = *(const float4*)(s0p);
  float4 a1 = *(const float4*)(s1p);
  float4 a2 = *(const float4*)(s2p);
  float4 n0 = *(const float4*)(s0p + 4);
  float4 n1 = *(const float4*)(s1p + 4);
  float4 n2 = *(const float4*)(s2p + 4);

  float m = 0.f;
  for (int t4 = 0; t4 < 256; ++t4) {
    float4 w0 = a0, w1 = a1, w2 = a2;
    a0 = n0; a1 = n1; a2 = n2;
    if (t4 < 254) {
      n0 = *(const float4*)(s0p + t4 * 4 + 8);
      n1 = *(const float4*)(s1p + t4 * 4 + 8);
      n2 = *(const float4*)(s2p + t4 * 4 + 8);
    }
    const int tt = t4 * 4;
    m = w0.x * m + (w1.x + w2.x * (float)(tt + 1)) * inv; mb[tt]     = m;
    m = w0.y * m + (w1.y + w2.y * (float)(tt + 2)) * inv; mb[tt + 1] = m;
    m = w0.z * m + (w1.z + w2.z * (float)(tt + 3)) * inv; mb[tt + 2] = m;
    m = w0.w * m + (w1.w + w2.w * (float)(tt + 4)) * inv; mb[tt + 3] = m;
  }
}

// ---------------------------------------------------------------------------
// K4: fused positional attention with 32x32x16 bf16 MFMA.
// context[b,j,:] = (sum_{i<=j} w_ji * x[b,i,:]) / max(||w_j||, 1e-12)
// x staged d-major in LDS (from xbf_t) so each B-fragment is one
// ds_read_b128. w generated on the fly in MFMA A-fragment layout.
// Block 256 thr = 4 waves: wave = (jh, dh); tile 64 j x 128 d; K-step 32 i.
// ---------------------------------------------------------------------------
static constexpr int TJ = 64, TD = 128, KI = 32, RS = 40;  // RS: LDS row stride (shorts)

__global__ __launch_bounds__(256) void k4_attn(
    const float* __restrict__ x, const unsigned short* __restrict__ xbf_t,
    int use_bf, const float* __restrict__ mu, const float* __restrict__ sigma,
    float* __restrict__ out)
{
  __shared__ unsigned short xsT[TD * RS];   // 10240 B
  __shared__ float snrm[2][32];
  __shared__ float sscl[2][32];

  const int b   = blockIdx.z;
  const int jt0 = blockIdx.x * TJ;
  const int dt0 = blockIdx.y * TD;
  const int tid = threadIdx.x;
  const int wave = tid >> 6, lane = tid & 63;
  const int jh = wave & 1, dh = wave >> 1;
  const int n32 = lane & 31, half = lane >> 5;
  const int jrow = jt0 + jh * 32 + n32;

  const float muv  = mu[b * cS + jrow];
  const float sg   = sigma[b * cS + jrow];
  const float invj = 1.f / (float)(jrow + 1);
  const float ce   = -0.72134752f / (sg * sg);   // -log2(e)/(2*sigma^2)

  float nrm2 = 0.f;
  floatx16 acc0 = (floatx16)0.f, acc1 = (floatx16)0.f;

  const int iend = jt0 + TJ;
  for (int i0 = 0; i0 < iend; i0 += KI) {
    __syncthreads();
    // ---- stage xsT[d][i] : 128 d-rows x 32 i (bf16) ----------------------
    if (use_bf) {
#pragma unroll
      for (int q = 0; q < 2; ++q) {
        const int cc = tid + q * 256;
        const int dl = cc >> 2, part = cc & 3;
        uint4 v = *(const uint4*)(xbf_t + ((size_t)(b * cD + dt0 + dl)) * cS + i0 + part * 8);
        *(uint4*)&xsT[dl * RS + part * 8] = v;
      }
    } else {
#pragma unroll
      for (int q = 0; q < 2; ++q) {
        const int cc = tid + q * 256;
        const int i = cc & 31, d8 = cc >> 5;
        const float* xp = x + ((size_t)(b * cS + i0 + i)) * cD + dt0 + d8 * 8;
        float4 f0 = *(const float4*)xp;
        float4 f1 = *(const float4*)(xp + 4);
        float vv[8] = {f0.x, f0.y, f0.z, f0.w, f1.x, f1.y, f1.z, f1.w};
#pragma unroll
        for (int e = 0; e < 8; ++e) {
          union { float f; unsigned u; } cv; cv.f = vv[e];
          xsT[(d8 * 8 + e) * RS + i] = (unsigned short)(cv.u >> 16);
        }
      }
    }
    __syncthreads();

    // ---- A fragments (w values), kc = 0,1 --------------------------------
    short8 af0, af1;
#pragma unroll
    for (int kc = 0; kc < 2; ++kc) {
      short8 af;
#pragma unroll
      for (int e = 0; e < 8; ++e) {
        const int ig = i0 + kc * 16 + half * 8 + e;
        const float d = fmaf((float)ig, invj, -muv);
        float w = __builtin_amdgcn_exp2f(ce * d * d);
        w = (ig <= jrow) ? w : 0.f;
        nrm2 += w * w;
        union { float f; unsigned u; } cv; cv.f = w;
        af[e] = (short)(cv.u >> 16);
      }
      if (kc == 0) af0 = af; else af1 = af;
    }

    // ---- B fragments (one ds_read_b128 each) + MFMA ----------------------
    const int rbase = dh * 64 + n32;
    short8 b00 = *(const short8*)&xsT[(rbase)      * RS + half * 8];
    short8 b01 = *(const short8*)&xsT[(rbase)      * RS + 16 + half * 8];
    short8 b10 = *(const short8*)&xsT[(rbase + 32) * RS + half * 8];
    short8 b11 = *(const short8*)&xsT[(rbase + 32) * RS + 16 + half * 8];
    acc0 = __builtin_amdgcn_mfma_f32_32x32x16_bf16(af0, b00, acc0, 0, 0, 0);
    acc0 = __builtin_amdgcn_mfma_f32_32x32x16_bf16(af1, b01, acc0, 0, 0, 0);
    acc1 = __builtin_amdgcn_mfma_f32_32x32x16_bf16(af0, b10, acc1, 0, 0, 0);
    acc1 = __builtin_amdgcn_mfma_f32_32x32x16_bf16(af1, b11, acc1, 0, 0, 0);
  }

  // ---- norms --------------------------------------------------------------
  nrm2 += __shfl_xor(nrm2, 32);
  if (wave < 2 && half == 0) snrm[jh][n32] = nrm2;
  __syncthreads();
  if (tid < 64)
    sscl[tid >> 5][tid & 31] =
        __builtin_amdgcn_rcpf(fmaxf(sqrtf(snrm[tid >> 5][tid & 31]), 1e-12f));
  __syncthreads();

  float srow[16];
#pragma unroll
  for (int reg = 0; reg < 16; ++reg) {
    const int row = (reg & 3) + 8 * (reg >> 2) + 4 * half;
    srow[reg] = sscl[jh][row];
  }
#pragma unroll
  for (int reg = 0; reg < 16; ++reg) {
    const int row = (reg & 3) + 8 * (reg >> 2) + 4 * half;
    const int jg = jt0 + jh * 32 + row;
    const int d0 = dt0 + dh * 64 + n32;
    out[((size_t)(b * cS + jg)) * cD + d0]      = acc0[reg] * srow[reg];
    out[((size_t)(b * cS + jg)) * cD + d0 + 32] = acc1[reg] * srow[reg];
  }
}

// ---------------------------------------------------------------------------
extern "C" void kernel_launch(void* const* d_in, const int* in_sizes, int n_in,
                              void* d_out, int out_size, void* d_ws, size_t ws_size,
                              hipStream_t stream) {
  const float* x     = (const float*)d_in[0];
  const float* W_ih  = (const float*)d_in[1];
  const float* W_hh  = (const float*)d_in[2];
  const float* b_ih  = (const float*)d_in[3];
  const float* b_hh  = (const float*)d_in[4];
  const float* W_mu  = (const float*)d_in[5];
  const float* b_mu  = (const float*)d_in[6];
  const float* W_sig = (const float*)d_in[7];
  const float* b_sig = (const float*)d_in[8];
  float* out = (float*)d_out;

  char* ws = (char*)d_ws;
  const size_t off_xg  = 0;                                   // 16*80*1024*4
  const size_t off_h   = off_xg  + (size_t)cB*cS*cG*4;
  const size_t off_muw = off_h   + (size_t)cB*cS*cPE*4;
  const size_t off_sig = off_muw + (size_t)cB*cS*3*4;
  const size_t off_mu  = off_sig + (size_t)cB*cS*4;
  const size_t off_xbf = off_mu  + (size_t)cB*cS*4;
  const size_t need_bf = off_xbf + (size_t)cB*cS*cD*2;

  float* xgT   = (float*)(ws + off_xg);
  float* hbuf  = (float*)(ws + off_h);
  float* muwT  = (float*)(ws + off_muw);
  float* sigma = (float*)(ws + off_sig);
  float* mu    = (float*)(ws + off_mu);
  unsigned short* xbf_t = (unsigned short*)(ws + off_xbf);
  const int use_bf = (ws_size >= need_bf) ? 1 : 0;

  k1_xg  <<<dim3(cB * cS / 64), dim3(256), 0, stream>>>(x, W_ih, b_ih, b_hh, xgT, xbf_t, use_bf);
  k2_lstm<<<dim3(cB),           dim3(64),  0, stream>>>(xgT, W_hh, hbuf);
  k3a_muw<<<dim3(cB * cS / 256), dim3(256), 0, stream>>>(hbuf, W_mu, b_mu, W_sig, b_sig, muwT, sigma);
  k3b_mu <<<dim3(1),            dim3(64),  0, stream>>>(muwT, mu);
  k4_attn<<<dim3(cS/TJ, cD/TD, cB), dim3(256), 0, stream>>>(x, xbf_t, use_bf, mu, sigma, out);
}

// Round 4
// 517.884 us; speedup vs baseline: 2.1896x; 1.1473x over previous
//
#include <hip/hip_runtime.h>

#define DEVFN __device__ __forceinline__

static constexpr int cB  = 16;
static constexpr int cS  = 1024;
static constexpr int cD  = 1024;
static constexpr int cPE = 20;
static constexpr int cG  = 80;   // 4*PE

typedef float  floatx2  __attribute__((ext_vector_type(2)));
typedef float  floatx4  __attribute__((ext_vector_type(4)));
typedef float  floatx16 __attribute__((ext_vector_type(16)));
typedef short  short8   __attribute__((ext_vector_type(8)));

DEVFN unsigned pack_bf(float a, float b) {
  union { float f; unsigned u; } ua, ub; ua.f = a; ub.f = b;
  return (ua.u >> 16) | (ub.u & 0xffff0000u);
}

// ---------------------------------------------------------------------------
// K1: xgT[b][g][t] = (x @ W_ih^T + b_ih + b_hh) * gate_scale(g), transposed
//     for k2's streaming loads. gate_scale = 2*log2e for g in [40,60) (the
//     tanh gate), log2e otherwise.
//     + fused emit of x transposed to bf16: xbf_t[b][d][s] for k4.
// Tile: 64 rows x 80 gates, K-chunks of 64. Grid = 256 blocks.
// ---------------------------------------------------------------------------
static constexpr int K1_XS = 68;  // LDS row stride (floats)

__global__ __launch_bounds__(256) void k1_xg(
    const float* __restrict__ x, const float* __restrict__ W_ih,
    const float* __restrict__ b_ih, const float* __restrict__ b_hh,
    float* __restrict__ xgT, unsigned short* __restrict__ xbf_t, int use_bf)
{
  __shared__ float xs[64 * K1_XS];   // 17408 B
  __shared__ float wsm[80 * K1_XS];  // 21760 B

  const int t  = threadIdx.x;
  const int rg = t >> 4, cg = t & 15;
  const int r0 = rg * 4, c0 = cg * 5;
  const int row0 = blockIdx.x * 64;
  const int b  = row0 >> 10;
  const int s0 = row0 & 1023;

  floatx2 acc[4][5];
#pragma unroll
  for (int q = 0; q < 4; ++q)
#pragma unroll
    for (int cc = 0; cc < 5; ++cc) { acc[q][cc].x = 0.f; acc[q][cc].y = 0.f; }

  for (int kc = 0; kc < 16; ++kc) {
    const int k0 = kc * 64;
    // ---- stage x tile: 64 rows x 64 k ------------------------------------
    {
      const int sr = t >> 2, sc = t & 3;
      const float4* src = (const float4*)(x + (size_t)(row0 + sr) * cD + k0 + sc * 16);
      float4 v0 = src[0], v1 = src[1], v2 = src[2], v3 = src[3];
      float4* dst = (float4*)&xs[sr * K1_XS + sc * 16];
      dst[0] = v0; dst[1] = v1; dst[2] = v2; dst[3] = v3;
    }
    // ---- stage W tile: 80 gates x 64 k -----------------------------------
#pragma unroll
    for (int q = 0; q < 5; ++q) {
      const int id = t + q * 256;          // 0..1279
      const int g = id >> 4, c4 = id & 15;
      float4 wv = *(const float4*)(W_ih + (size_t)g * cD + k0 + c4 * 4);
      *(float4*)&wsm[g * K1_XS + c4 * 4] = wv;
    }
    __syncthreads();

    // ---- transposed bf16 emit: xbf_t[b][k0+dl][s0 + 16*sc4 + e] ----------
    if (use_bf) {
      const int dl = t >> 2, sc4 = t & 3;
      float v[16];
#pragma unroll
      for (int e = 0; e < 16; ++e) v[e] = xs[(sc4 * 16 + e) * K1_XS + dl];
      unsigned u[8];
#pragma unroll
      for (int p = 0; p < 8; ++p) u[p] = pack_bf(v[2 * p], v[2 * p + 1]);
      unsigned short* dstp = xbf_t + ((size_t)(b * cD + k0 + dl)) * cS + s0 + sc4 * 16;
      *(uint4*)dstp       = make_uint4(u[0], u[1], u[2], u[3]);
      *(uint4*)(dstp + 8) = make_uint4(u[4], u[5], u[6], u[7]);
    }

    // ---- compute: 32 x (9 ds_read_b64 + 20 pk_fma) -----------------------
#pragma unroll 4
    for (int k2 = 0; k2 < 32; ++k2) {
      floatx2 xv[4], wv[5];
#pragma unroll
      for (int q = 0; q < 4; ++q)
        xv[q] = *(const floatx2*)&xs[(r0 + q) * K1_XS + 2 * k2];
#pragma unroll
      for (int cc = 0; cc < 5; ++cc)
        wv[cc] = *(const floatx2*)&wsm[(c0 + cc) * K1_XS + 2 * k2];
#pragma unroll
      for (int q = 0; q < 4; ++q)
#pragma unroll
        for (int cc = 0; cc < 5; ++cc)
          acc[q][cc] += xv[q] * wv[cc];
    }
    __syncthreads();
  }

  // ---- epilogue: scaled, biased, transposed stores (float4 over t) -------
#pragma unroll
  for (int cc = 0; cc < 5; ++cc) {
    const int g = c0 + cc;
    const float sc = (g >= 40 && g < 60) ? 2.88539008f : 1.44269504f;
    const float bs = b_ih[g] + b_hh[g];
    float4 v;
    v.x = (acc[0][cc].x + acc[0][cc].y + bs) * sc;
    v.y = (acc[1][cc].x + acc[1][cc].y + bs) * sc;
    v.z = (acc[2][cc].x + acc[2][cc].y + bs) * sc;
    v.w = (acc[3][cc].x + acc[3][cc].y + bs) * sc;
    *(float4*)&xgT[((size_t)(b * cG + g)) * cS + s0 + r0] = v;
  }
}

// ---------------------------------------------------------------------------
// K2: LSTM scan, lane-parallel gates. One wave per batch.
// Lane l<60 owns W_hh row l (i:0-19, f:20-39, g:40-59); lanes 0-19 also own
// o-row 60+j. Streams from xgT are pre-scaled+biased. Unified activation:
// sigmoid = e/(e+1), tanh = (e-1)/(e+1), e = exp2(pre-scaled gate).
// Gate gather: 2 bpermutes. h broadcast: 1 ds_write + 5 ds_read_b128
// (single wave => DS-pipe program order, no s_barrier).
// ---------------------------------------------------------------------------
__global__ __launch_bounds__(64) void k2_lstm(
    const float* __restrict__ xgT, const float* __restrict__ W_hh,
    float* __restrict__ hbuf)
{
  const int b    = blockIdx.x;
  const int lane = threadIdx.x;
  const int l59  = lane < 60 ? lane : 59;
  const int j    = l59 % cPE;
  const bool isG = (l59 >= 40);
  const float LOG2E = 1.44269504f, TWOLOG2E = 2.88539008f;

  const float sA = isG ? TWOLOG2E : LOG2E;
  floatx2 wA[10], wB[10];
#pragma unroll
  for (int p = 0; p < 10; ++p) {
    wA[p].x = W_hh[l59 * cPE + 2 * p]     * sA;
    wA[p].y = W_hh[l59 * cPE + 2 * p + 1] * sA;
    wB[p].x = W_hh[(60 + j) * cPE + 2 * p]     * LOG2E;
    wB[p].y = W_hh[(60 + j) * cPE + 2 * p + 1] * LOG2E;
  }

  const float* baseA = xgT + ((size_t)(b * cG + l59)) * cS;
  const float* baseB = xgT + ((size_t)(b * cG + 60 + j)) * cS;

  // 4-slot rotation: slot s holds quad q0+s; reload for q+4 (16 steps ahead).
  // Trailing prefetches read <=64B past xgT's end -> hbuf region (safe).
  float4 bufA[4], bufB[4];
#pragma unroll
  for (int s = 0; s < 4; ++s) {
    bufA[s] = *(const float4*)(baseA + s * 4);
    bufB[s] = *(const float4*)(baseB + s * 4);
  }

  __shared__ float hsh[32];
  if (lane < 32) hsh[lane] = 0.f;
  __syncthreads();

  float c = 0.f;
  float* hb = hbuf + (size_t)b * cS * cPE + j;

  for (int q0 = 0; q0 < 256; q0 += 4) {
#pragma unroll
    for (int s = 0; s < 4; ++s) {
      const int q = q0 + s;
      const float4 gA4 = bufA[s];
      const float4 gB4 = bufB[s];
      bufA[s] = *(const float4*)(baseA + (q + 4) * 4);
      bufB[s] = *(const float4*)(baseB + (q + 4) * 4);
#pragma unroll
      for (int e = 0; e < 4; ++e) {
        const float geA = (e == 0) ? gA4.x : (e == 1) ? gA4.y : (e == 2) ? gA4.z : gA4.w;
        const float geB = (e == 0) ? gB4.x : (e == 1) ? gB4.y : (e == 2) ? gB4.z : gB4.w;

        // ---- h broadcast read (zeros on first step) ----------------------
        float4 h0 = *(const float4*)&hsh[0];
        float4 h1 = *(const float4*)&hsh[4];
        float4 h2 = *(const float4*)&hsh[8];
        float4 h3 = *(const float4*)&hsh[12];
        float4 h4 = *(const float4*)&hsh[16];
        floatx2 hv[10];
        hv[0].x = h0.x; hv[0].y = h0.y;  hv[1].x = h0.z; hv[1].y = h0.w;
        hv[2].x = h1.x; hv[2].y = h1.y;  hv[3].x = h1.z; hv[3].y = h1.w;
        hv[4].x = h2.x; hv[4].y = h2.y;  hv[5].x = h2.z; hv[5].y = h2.w;
        hv[6].x = h3.x; hv[6].y = h3.y;  hv[7].x = h3.z; hv[7].y = h3.w;
        hv[8].x = h4.x; hv[8].y = h4.y;  hv[9].x = h4.z; hv[9].y = h4.w;

        // ---- dots (2 depth-5 chains per stream) --------------------------
        floatx2 aA0, aA1, aB0, aB1;
        aA0.x = geA; aA0.y = 0.f; aA1.x = 0.f; aA1.y = 0.f;
        aB0.x = geB; aB0.y = 0.f; aB1.x = 0.f; aB1.y = 0.f;
#pragma unroll
        for (int p = 0; p < 5; ++p) {
          aA0 += wA[p] * hv[p];
          aA1 += wA[5 + p] * hv[5 + p];
          aB0 += wB[p] * hv[p];
          aB1 += wB[5 + p] * hv[5 + p];
        }
        const float gAv = (aA0.x + aA0.y) + (aA1.x + aA1.y);
        const float gBv = (aB0.x + aB0.y) + (aB1.x + aB1.y);

        // ---- activations -------------------------------------------------
        const float eA = __builtin_amdgcn_exp2f(fminf(gAv, 30.f));
        const float nA = isG ? (eA - 1.f) : eA;
        const float actA = nA * __builtin_amdgcn_rcpf(eA + 1.f);
        const float eB = __builtin_amdgcn_exp2f(fminf(gBv, 30.f));
        const float actB = eB * __builtin_amdgcn_rcpf(eB + 1.f);   // so

        // ---- gather + state update (valid on lanes < 20) -----------------
        const float sf = __shfl(actA, 20 + j);
        const float tg = __shfl(actA, 40 + j);
        c = sf * c + actA * tg;                   // actA = si on lanes<20
        const float ec = __builtin_amdgcn_exp2f(fminf(TWOLOG2E * c, 30.f));
        const float th = (ec - 1.f) * __builtin_amdgcn_rcpf(ec + 1.f);
        const float hj = actB * th;

        if (lane < cPE) {
          hb[(size_t)(q * 4 + e) * cPE] = hj;
          hsh[lane] = hj;
        }
        __builtin_amdgcn_wave_barrier();
      }
    }
  }
}

// ---------------------------------------------------------------------------
// K3a: muwT[g][r] = relu(h@W_mu^T + b_mu), sigma = sigmoid(h@W_sig^T + b_sig)
// SoA output for the scan kernel. Grid: 64 blocks x 256.
// ---------------------------------------------------------------------------
__global__ __launch_bounds__(256) void k3a_muw(
    const float* __restrict__ hbuf,
    const float* __restrict__ W_mu, const float* __restrict__ b_mu,
    const float* __restrict__ W_sig, const float* __restrict__ b_sig,
    float* __restrict__ muwT, float* __restrict__ sigma)
{
  __shared__ float sw[84];
  const int t = threadIdx.x;
  if (t < 60) sw[t] = W_mu[t];
  else if (t < 80) sw[t] = W_sig[t - 60];
  else if (t < 83) sw[t] = b_mu[t - 80];
  else if (t == 83) sw[t] = b_sig[0];
  __syncthreads();

  const int r = blockIdx.x * 256 + t;
  const float4* hp = (const float4*)(hbuf + (size_t)r * cPE);
  float h[20];
#pragma unroll
  for (int q2 = 0; q2 < 5; ++q2) {
    float4 v = hp[q2];
    h[4 * q2] = v.x; h[4 * q2 + 1] = v.y; h[4 * q2 + 2] = v.z; h[4 * q2 + 3] = v.w;
  }
  float m0 = sw[80], m1 = sw[81], m2 = sw[82], sg = sw[83];
#pragma unroll
  for (int p = 0; p < 20; ++p) {
    m0 += sw[p]      * h[p];
    m1 += sw[20 + p] * h[p];
    m2 += sw[40 + p] * h[p];
    sg += sw[60 + p] * h[p];
  }
  muwT[r]                 = fmaxf(m0, 0.f);
  muwT[cB * cS + r]       = fmaxf(m1, 0.f);
  muwT[2 * cB * cS + r]   = fmaxf(m2, 0.f);
  sigma[r] = __builtin_amdgcn_rcpf(1.f + __builtin_amdgcn_exp2f(-1.44269504f * sg));
}

// ---------------------------------------------------------------------------
// K3b: sequential mu recurrence, 16 chains (one lane each), float4 prefetch.
// ---------------------------------------------------------------------------
__global__ __launch_bounds__(64) void k3b_mu(
    const float* __restrict__ muwT, float* __restrict__ mu)
{
  const int t = threadIdx.x;
  if (t >= cB) return;
  const float* s0p = muwT + (size_t)t * cS;
  const float* s1p = muwT + cB * cS + (size_t)t * cS;
  const float* s2p = muwT + 2 * cB * cS + (size_t)t * cS;
  float* mb = mu + (size_t)t * cS;
  const float inv = 1.f / (float)cS;

  float4 a0 = *(const float4*)(s0p);
  float4 a1 = *(const float4*)(s1p);
  float4 a2 = *(const float4*)(s2p);
  float4 n0 = *(const float4*)(s0p + 4);
  float4 n1 = *(const float4*)(s1p + 4);
  float4 n2 = *(const float4*)(s2p + 4);

  float m = 0.f;
  for (int t4 = 0; t4 < 256; ++t4) {
    float4 w0 = a0, w1 = a1, w2 = a2;
    a0 = n0; a1 = n1; a2 = n2;
    if (t4 < 254) {
      n0 = *(const float4*)(s0p + t4 * 4 + 8);
      n1 = *(const float4*)(s1p + t4 * 4 + 8);
      n2 = *(const float4*)(s2p + t4 * 4 + 8);
    }
    const int tt = t4 * 4;
    m = w0.x * m + (w1.x + w2.x * (float)(tt + 1)) * inv; mb[tt]     = m;
    m = w0.y * m + (w1.y + w2.y * (float)(tt + 2)) * inv; mb[tt + 1] = m;
    m = w0.z * m + (w1.z + w2.z * (float)(tt + 3)) * inv; mb[tt + 2] = m;
    m = w0.w * m + (w1.w + w2.w * (float)(tt + 4)) * inv; mb[tt + 3] = m;
  }
}

// ---------------------------------------------------------------------------
// K4: fused positional attention with 32x32x16 bf16 MFMA.
// context[b,j,:] = (sum_{i<=j} w_ji * x[b,i,:]) / max(||w_j||, 1e-12)
// x staged d-major in LDS (from xbf_t) so each B-fragment is one
// ds_read_b128. w generated on the fly in MFMA A-fragment layout.
// Block 256 thr = 4 waves: wave = (jh, dh); tile 64 j x 128 d; K-step 32 i.
// ---------------------------------------------------------------------------
static constexpr int TJ = 64, TD = 128, KI = 32, RS = 40;  // RS: LDS row stride (shorts)

__global__ __launch_bounds__(256) void k4_attn(
    const float* __restrict__ x, const unsigned short* __restrict__ xbf_t,
    int use_bf, const float* __restrict__ mu, const float* __restrict__ sigma,
    float* __restrict__ out)
{
  __shared__ unsigned short xsT[TD * RS];   // 10240 B
  __shared__ float snrm[2][32];
  __shared__ float sscl[2][32];

  const int b   = blockIdx.z;
  const int jt0 = blockIdx.x * TJ;
  const int dt0 = blockIdx.y * TD;
  const int tid = threadIdx.x;
  const int wave = tid >> 6, lane = tid & 63;
  const int jh = wave & 1, dh = wave >> 1;
  const int n32 = lane & 31, half = lane >> 5;
  const int jrow = jt0 + jh * 32 + n32;

  const float muv  = mu[b * cS + jrow];
  const float sg   = sigma[b * cS + jrow];
  const float invj = 1.f / (float)(jrow + 1);
  const float ce   = -0.72134752f / (sg * sg);   // -log2(e)/(2*sigma^2)

  float nrm2 = 0.f;
  floatx16 acc0 = (floatx16)0.f, acc1 = (floatx16)0.f;

  const int iend = jt0 + TJ;
  for (int i0 = 0; i0 < iend; i0 += KI) {
    __syncthreads();
    // ---- stage xsT[d][i] : 128 d-rows x 32 i (bf16) ----------------------
    if (use_bf) {
#pragma unroll
      for (int q = 0; q < 2; ++q) {
        const int cc = tid + q * 256;
        const int dl = cc >> 2, part = cc & 3;
        uint4 v = *(const uint4*)(xbf_t + ((size_t)(b * cD + dt0 + dl)) * cS + i0 + part * 8);
        *(uint4*)&xsT[dl * RS + part * 8] = v;
      }
    } else {
#pragma unroll
      for (int q = 0; q < 2; ++q) {
        const int cc = tid + q * 256;
        const int i = cc & 31, d8 = cc >> 5;
        const float* xp = x + ((size_t)(b * cS + i0 + i)) * cD + dt0 + d8 * 8;
        float4 f0 = *(const float4*)xp;
        float4 f1 = *(const float4*)(xp + 4);
        float vv[8] = {f0.x, f0.y, f0.z, f0.w, f1.x, f1.y, f1.z, f1.w};
#pragma unroll
        for (int e = 0; e < 8; ++e) {
          union { float f; unsigned u; } cv; cv.f = vv[e];
          xsT[(d8 * 8 + e) * RS + i] = (unsigned short)(cv.u >> 16);
        }
      }
    }
    __syncthreads();

    // ---- A fragments (w values), kc = 0,1 --------------------------------
    short8 af0, af1;
#pragma unroll
    for (int kc = 0; kc < 2; ++kc) {
      short8 af;
#pragma unroll
      for (int e = 0; e < 8; ++e) {
        const int ig = i0 + kc * 16 + half * 8 + e;
        const float d = fmaf((float)ig, invj, -muv);
        float w = __builtin_amdgcn_exp2f(ce * d * d);
        w = (ig <= jrow) ? w : 0.f;
        nrm2 += w * w;
        union { float f; unsigned u; } cv; cv.f = w;
        af[e] = (short)(cv.u >> 16);
      }
      if (kc == 0) af0 = af; else af1 = af;
    }

    // ---- B fragments (one ds_read_b128 each) + MFMA ----------------------
    const int rbase = dh * 64 + n32;
    short8 b00 = *(const short8*)&xsT[(rbase)      * RS + half * 8];
    short8 b01 = *(const short8*)&xsT[(rbase)      * RS + 16 + half * 8];
    short8 b10 = *(const short8*)&xsT[(rbase + 32) * RS + half * 8];
    short8 b11 = *(const short8*)&xsT[(rbase + 32) * RS + 16 + half * 8];
    acc0 = __builtin_amdgcn_mfma_f32_32x32x16_bf16(af0, b00, acc0, 0, 0, 0);
    acc0 = __builtin_amdgcn_mfma_f32_32x32x16_bf16(af1, b01, acc0, 0, 0, 0);
    acc1 = __builtin_amdgcn_mfma_f32_32x32x16_bf16(af0, b10, acc1, 0, 0, 0);
    acc1 = __builtin_amdgcn_mfma_f32_32x32x16_bf16(af1, b11, acc1, 0, 0, 0);
  }

  // ---- norms --------------------------------------------------------------
  nrm2 += __shfl_xor(nrm2, 32);
  if (wave < 2 && half == 0) snrm[jh][n32] = nrm2;
  __syncthreads();
  if (tid < 64)
    sscl[tid >> 5][tid & 31] =
        __builtin_amdgcn_rcpf(fmaxf(sqrtf(snrm[tid >> 5][tid & 31]), 1e-12f));
  __syncthreads();

  float srow[16];
#pragma unroll
  for (int reg = 0; reg < 16; ++reg) {
    const int row = (reg & 3) + 8 * (reg >> 2) + 4 * half;
    srow[reg] = sscl[jh][row];
  }
#pragma unroll
  for (int reg = 0; reg < 16; ++reg) {
    const int row = (reg & 3) + 8 * (reg >> 2) + 4 * half;
    const int jg = jt0 + jh * 32 + row;
    const int d0 = dt0 + dh * 64 + n32;
    out[((size_t)(b * cS + jg)) * cD + d0]      = acc0[reg] * srow[reg];
    out[((size_t)(b * cS + jg)) * cD + d0 + 32] = acc1[reg] * srow[reg];
  }
}

// ---------------------------------------------------------------------------
extern "C" void kernel_launch(void* const* d_in, const int* in_sizes, int n_in,
                              void* d_out, int out_size, void* d_ws, size_t ws_size,
                              hipStream_t stream) {
  const float* x     = (const float*)d_in[0];
  const float* W_ih  = (const float*)d_in[1];
  const float* W_hh  = (const float*)d_in[2];
  const float* b_ih  = (const float*)d_in[3];
  const float* b_hh  = (const float*)d_in[4];
  const float* W_mu  = (const float*)d_in[5];
  const float* b_mu  = (const float*)d_in[6];
  const float* W_sig = (const float*)d_in[7];
  const float* b_sig = (const float*)d_in[8];
  float* out = (float*)d_out;

  char* ws = (char*)d_ws;
  const size_t off_xg  = 0;                                   // 16*80*1024*4
  const size_t off_h   = off_xg  + (size_t)cB*cS*cG*4;
  const size_t off_muw = off_h   + (size_t)cB*cS*cPE*4;
  const size_t off_sig = off_muw + (size_t)cB*cS*3*4;
  const size_t off_mu  = off_sig + (size_t)cB*cS*4;
  const size_t off_xbf = off_mu  + (size_t)cB*cS*4;
  const size_t need_bf = off_xbf + (size_t)cB*cS*cD*2;

  float* xgT   = (float*)(ws + off_xg);
  float* hbuf  = (float*)(ws + off_h);
  float* muwT  = (float*)(ws + off_muw);
  float* sigma = (float*)(ws + off_sig);
  float* mu    = (float*)(ws + off_mu);
  unsigned short* xbf_t = (unsigned short*)(ws + off_xbf);
  const int use_bf = (ws_size >= need_bf) ? 1 : 0;

  k1_xg  <<<dim3(cB * cS / 64), dim3(256), 0, stream>>>(x, W_ih, b_ih, b_hh, xgT, xbf_t, use_bf);
  k2_lstm<<<dim3(cB),           dim3(64),  0, stream>>>(xgT, W_hh, hbuf);
  k3a_muw<<<dim3(cB * cS / 256), dim3(256), 0, stream>>>(hbuf, W_mu, b_mu, W_sig, b_sig, muwT, sigma);
  k3b_mu <<<dim3(1),            dim3(64),  0, stream>>>(muwT, mu);
  k4_attn<<<dim3(cS/TJ, cD/TD, cB), dim3(256), 0, stream>>>(x, xbf_t, use_bf, mu, sigma, out);
}